// Round 4
// baseline (662.311 us; speedup 1.0000x reference)
//
#include <hip/hip_runtime.h>

constexpr int HD = 128;    // hidden size
constexpr int BROWS = 64;  // rows per bucket == rows per mega-block
constexpr int CAP = 1536;  // LDS sorted-edge capacity per bucket

__device__ __forceinline__ int rl(int v, int j) {
    return __builtin_amdgcn_readlane(v, j);
}
__device__ __forceinline__ float rlf(int v, int j) {
    return __uint_as_float((unsigned)__builtin_amdgcn_readlane(v, j));
}
__device__ __forceinline__ unsigned f2bf(float f) {  // f32 -> bf16 bits, RNE
    unsigned u = __float_as_uint(f);
    return (u + 0x7fffu + ((u >> 16) & 1u)) >> 16;
}

// ---------------------------------------------------------------------------
// prep: three block-ranges in one launch.
//  [0, PB)     : per-row L1 norm of x; pack xb = bf16x2(x * rnorm)
//  [PB, PB+64) : Wp pair-interleave  Wp[k2*256+2h+j] = W[h][2k2+j]
//  [PB+64, ..) : bucket histogram of A_rows>>6 (1563 counters)
// ---------------------------------------------------------------------------
__global__ void prep_kernel(const float* __restrict__ x,
                            unsigned* __restrict__ xb,
                            const float* __restrict__ W,
                            float* __restrict__ Wp,
                            const int* __restrict__ rows,
                            int* __restrict__ bcnt,
                            int N, int E, int PB) {
    int bid = blockIdx.x;
    if (bid < PB) {
        int row = bid * 4 + (threadIdx.x >> 6);
        int lane = threadIdx.x & 63;
        if (row >= N) return;
        float2 v = *((const float2*)(x + (size_t)row * HD) + lane);
        float s = fabsf(v.x) + fabsf(v.y);
#pragma unroll
        for (int m = 1; m < 64; m <<= 1) s += __shfl_xor(s, m, 64);
        float rn = 1.0f / fmaxf(s, 1e-12f);
        unsigned lo = f2bf(v.x * rn), hi = f2bf(v.y * rn);
        xb[(size_t)row * 64 + lane] = lo | (hi << 16);
    } else if (bid < PB + 64) {
        int t = (bid - PB) * 256 + threadIdx.x;  // 0..16383
        int k2 = t >> 8, rem = t & 255, h = rem >> 1, j = rem & 1;
        Wp[t] = W[h * HD + 2 * k2 + j];
    } else {
        int base = (bid - PB - 64) * 1024 + threadIdx.x;
#pragma unroll
        for (int i = 0; i < 4; ++i) {
            int e = base + i * 256;
            if (e < E) atomicAdd(&bcnt[rows[e] >> 6], 1);
        }
    }
}

// ---------------------------------------------------------------------------
// bscan: single-block exclusive scan of NB bucket counts (NB <= 2048).
// Writes bbase (CSR bucket base) and bcursor (scatter cursors).
// ---------------------------------------------------------------------------
__global__ void bscan_kernel(const int* __restrict__ bcnt,
                             int* __restrict__ bbase,
                             int* __restrict__ bcursor, int NB) {
    __shared__ int lds[1024];
    int t = threadIdx.x;
    int i0 = 2 * t, i1 = 2 * t + 1;
    int c0 = (i0 < NB) ? bcnt[i0] : 0;
    int c1 = (i1 < NB) ? bcnt[i1] : 0;
    int s = c0 + c1;
    lds[t] = s;
    __syncthreads();
    for (int off = 1; off < 1024; off <<= 1) {
        int add = (t >= off) ? lds[t - off] : 0;
        __syncthreads();
        lds[t] += add;
        __syncthreads();
    }
    int excl = lds[t] - s;
    if (i0 < NB) { bbase[i0] = excl; bcursor[i0] = excl; }
    if (i1 < NB) { bbase[i1] = excl + c0; bcursor[i1] = excl + c0; }
}

// ---------------------------------------------------------------------------
// bscatter: edges -> bucket-grouped staging array.
// meta.x = col | (rowlocal<<17)   (col < 2^17, rowlocal < 64)
// meta.y = f32 bits of edge value
// Writes land densely inside each bucket's ~8KB region (good L2 locality).
// ---------------------------------------------------------------------------
__global__ void bscatter_kernel(const int* __restrict__ rows,
                                const int* __restrict__ cols,
                                const float* __restrict__ vals,
                                int* __restrict__ bcursor,
                                int2* __restrict__ bstage, int E) {
    int base = blockIdx.x * 1024 + threadIdx.x;
#pragma unroll
    for (int i = 0; i < 4; ++i) {
        int e = base + i * 256;
        if (e >= E) break;
        int r = rows[e], c = cols[e];
        float v = vals[e];
        int p = atomicAdd(&bcursor[r >> 6], 1);
        bstage[p] = make_int2(c | ((r & 63) << 17), __float_as_int(v));
    }
}

// ---------------------------------------------------------------------------
// mega: per 64-row bucket (1024 threads = 16 waves x 4 rows):
//  - load bucket edges (<=2048) to registers
//  - in-LDS 64-bin counting sort -> local CSR in 12KB LDS (spill->bstage)
//  - stage Wp into 64KB LDS
//  - gather bf16 xb rows via readlane-broadcast metadata from LDS
//  - g = f @ W^T + b (readlane GEMM), L1-normalize, relu, residual, store
// ---------------------------------------------------------------------------
__global__ void __launch_bounds__(1024) mega_kernel(
    const float* __restrict__ x, const unsigned* __restrict__ xb,
    int2* bstage, const int* __restrict__ bbase, const int* __restrict__ bcnt,
    const float* __restrict__ Wp, const float* __restrict__ b,
    const float* __restrict__ tsp, float* __restrict__ out, int N) {
    __shared__ float wlds[HD * HD];  // 64 KiB
    __shared__ int2 sorted[CAP];     // 12 KiB
    __shared__ int lcnt[BROWS], lbeg[BROWS], lcur[BROWS];

    int tid = threadIdx.x;
    int bid = blockIdx.x;
    int bb = bbase[bid];
    int ct = bcnt[bid];

    if (tid < BROWS) lcnt[tid] = 0;

    // phase 1: bucket edges -> registers
    int2 m0 = make_int2(0, 0), m1 = make_int2(0, 0);
    bool e0 = tid < ct, e1 = tid + 1024 < ct;
    if (e0) m0 = bstage[bb + tid];
    if (e1) m1 = bstage[bb + tid + 1024];
    __syncthreads();  // lcnt zeroed + all bstage reads drained (vmcnt(0))

    // phase 2: LDS histogram of local rows
    if (e0) atomicAdd(&lcnt[(m0.x >> 17) & 63], 1);
    if (e1) atomicAdd(&lcnt[(m1.x >> 17) & 63], 1);
    __syncthreads();

    // phase 3: wave 0 exclusive-scans the 64 counts
    if (tid < 64) {
        int c = lcnt[tid];
        int s = c;
#pragma unroll
        for (int m = 1; m < 64; m <<= 1) {
            int t2 = __shfl_up(s, m, 64);
            if (tid >= m) s += t2;
        }
        lbeg[tid] = s - c;
        lcur[tid] = s - c;
    }
    __syncthreads();

    // phase 4: scatter edges into LDS-sorted local CSR (spill to bstage)
    if (e0) {
        int p = atomicAdd(&lcur[(m0.x >> 17) & 63], 1);
        if (p < CAP) sorted[p] = m0; else bstage[bb + p] = m0;
    }
    if (e1) {
        int p = atomicAdd(&lcur[(m1.x >> 17) & 63], 1);
        if (p < CAP) sorted[p] = m1; else bstage[bb + p] = m1;
    }
    // phase 5: stage Wp (independent LDS region, no barrier needed before)
    {
        const float4* s4 = (const float4*)Wp;
        float4* d4 = (float4*)wlds;
        for (int i = tid; i < HD * HD / 4; i += 1024) d4[i] = s4[i];
    }
    __syncthreads();  // last barrier

    int lane = tid & 63;
    int wid = tid >> 6;
    int r0 = bid * BROWS + wid * 4;
    if (r0 >= N) return;
    float ts = tsp[0];
    float b0 = b[2 * lane], b1 = b[2 * lane + 1];

    // ---- gather: accumulate 4 f-rows in registers ----
    float a0[4] = {0.f, 0.f, 0.f, 0.f}, a1[4] = {0.f, 0.f, 0.f, 0.f};
#pragma unroll
    for (int rr = 0; rr < 4; ++rr) {
        int row = r0 + rr;
        if (row >= N) break;
        int lr = wid * 4 + rr;
        int beg = lbeg[lr], cnt = lcnt[lr];
        float p0 = 0.f, q0 = 0.f, p1 = 0.f, q1 = 0.f;
        for (int jb = 0; jb < cnt; jb += 64) {
            int rem = cnt - jb;
            if (rem > 64) rem = 64;
            int2 meta = make_int2(0, 0);
            if (lane < rem) {
                int pidx = beg + jb + lane;
                meta = (pidx < CAP) ? sorted[pidx] : bstage[bb + pidx];
            }
            int j = 0;
            for (; j + 4 <= rem; j += 4) {
                int c0 = rl(meta.x, j) & 0x1FFFF;
                int c1 = rl(meta.x, j + 1) & 0x1FFFF;
                int c2 = rl(meta.x, j + 2) & 0x1FFFF;
                int c3 = rl(meta.x, j + 3) & 0x1FFFF;
                float s0 = rlf(meta.y, j), s1 = rlf(meta.y, j + 1);
                float s2 = rlf(meta.y, j + 2), s3 = rlf(meta.y, j + 3);
                unsigned u0 = xb[(size_t)c0 * 64 + lane];
                unsigned u1 = xb[(size_t)c1 * 64 + lane];
                unsigned u2 = xb[(size_t)c2 * 64 + lane];
                unsigned u3 = xb[(size_t)c3 * 64 + lane];
                p0 = fmaf(__uint_as_float(u0 << 16), s0, p0);
                q0 = fmaf(__uint_as_float(u0 & 0xffff0000u), s0, q0);
                p1 = fmaf(__uint_as_float(u1 << 16), s1, p1);
                q1 = fmaf(__uint_as_float(u1 & 0xffff0000u), s1, q1);
                p0 = fmaf(__uint_as_float(u2 << 16), s2, p0);
                q0 = fmaf(__uint_as_float(u2 & 0xffff0000u), s2, q0);
                p1 = fmaf(__uint_as_float(u3 << 16), s3, p1);
                q1 = fmaf(__uint_as_float(u3 & 0xffff0000u), s3, q1);
            }
            for (; j < rem; ++j) {
                int c0 = rl(meta.x, j) & 0x1FFFF;
                float s0 = rlf(meta.y, j);
                unsigned u0 = xb[(size_t)c0 * 64 + lane];
                p0 = fmaf(__uint_as_float(u0 << 16), s0, p0);
                q0 = fmaf(__uint_as_float(u0 & 0xffff0000u), s0, q0);
            }
        }
        a0[rr] = p0 + p1;
        a1[rr] = q0 + q1;
    }

    // ---- GEMM: g[c] = dot(f, W[c,:]) for c = 2*lane, 2*lane+1 ----
    float g0[4] = {0.f, 0.f, 0.f, 0.f}, g1[4] = {0.f, 0.f, 0.f, 0.f};
#pragma unroll 8
    for (int k2 = 0; k2 < 64; ++k2) {
        float4 w = *((const float4*)(wlds + k2 * 256) + lane);
#pragma unroll
        for (int rr = 0; rr < 4; ++rr) {
            float fk0 = __uint_as_float(
                __builtin_amdgcn_readlane(__float_as_uint(a0[rr]), k2));
            float fk1 = __uint_as_float(
                __builtin_amdgcn_readlane(__float_as_uint(a1[rr]), k2));
            g0[rr] = fmaf(fk0, w.x, g0[rr]);
            g0[rr] = fmaf(fk1, w.y, g0[rr]);
            g1[rr] = fmaf(fk0, w.z, g1[rr]);
            g1[rr] = fmaf(fk1, w.w, g1[rr]);
        }
    }

    // ---- epilogue: bias, L1 normalize, relu, residual ----
#pragma unroll
    for (int rr = 0; rr < 4; ++rr) {
        int row = r0 + rr;
        if (row >= N) break;
        float G0 = g0[rr] + b0, G1 = g1[rr] + b1;
        float s = fabsf(G0) + fabsf(G1);
#pragma unroll
        for (int m = 1; m < 64; m <<= 1) s += __shfl_xor(s, m, 64);
        float rn = 1.0f / fmaxf(s, 1e-12f);
        G0 = fmaxf(G0 * rn, 0.f);
        G1 = fmaxf(G1 * rn, 0.f);
        float2 xv = *((const float2*)(x + (size_t)row * HD) + lane);
        float2 o;
        o.x = fmaf(ts, G0, xv.x);
        o.y = fmaf(ts, G1, xv.y);
        *((float2*)(out + (size_t)row * HD) + lane) = o;
    }
}

extern "C" void kernel_launch(void* const* d_in, const int* in_sizes, int n_in,
                              void* d_out, int out_size, void* d_ws,
                              size_t ws_size, hipStream_t stream) {
    const float* x = (const float*)d_in[0];
    const int* Ar = (const int*)d_in[1];
    const int* Ac = (const int*)d_in[2];
    const float* Av = (const float*)d_in[3];
    const float* W = (const float*)d_in[4];
    const float* b = (const float*)d_in[5];
    const float* ts = (const float*)d_in[6];

    int N = in_sizes[0] / HD;
    int E = in_sizes[1];
    float* out = (float*)d_out;

    int NB = (N + BROWS - 1) / BROWS;  // buckets == mega blocks

    char* ws = (char*)d_ws;
    size_t o = 0;
    auto take = [&](size_t bytes) {
        void* p = ws + o;
        o += (bytes + 511) & ~(size_t)511;
        return p;
    };
    int* bcnt = (int*)take((size_t)NB * 4);
    int* bbase = (int*)take((size_t)NB * 4);
    int* bcursor = (int*)take((size_t)NB * 4);
    float* Wp = (float*)take((size_t)HD * HD * 4);
    unsigned* xb = (unsigned*)take((size_t)N * 64 * 4);
    int2* bstage = (int2*)take((size_t)E * 8);
    // total ~38.5 MB (round-3 run proved ws >= ~52 MB)

    hipMemsetAsync(bcnt, 0, (size_t)NB * 4, stream);

    int PB = (N + 3) / 4;
    int HB = (E + 1023) / 1024;
    prep_kernel<<<PB + 64 + HB, 256, 0, stream>>>(x, xb, W, Wp, Ar, bcnt, N, E,
                                                  PB);
    bscan_kernel<<<1, 1024, 0, stream>>>(bcnt, bbase, bcursor, NB);
    bscatter_kernel<<<(E + 1023) / 1024, 256, 0, stream>>>(Ar, Ac, Av, bcursor,
                                                           bstage, E);
    mega_kernel<<<NB, 1024, 0, stream>>>(x, xb, bstage, bbase, bcnt, Wp, b, ts,
                                         out, N);
}

// Round 5
// 229.163 us; speedup vs baseline: 2.8901x; 2.8901x over previous
//
#include <hip/hip_runtime.h>

constexpr int HD = 128;    // hidden size
constexpr int BROWS = 64;  // rows per bucket == rows per mega-block
constexpr int CAP = 1536;  // LDS sorted-edge capacity per bucket
constexpr int NBMAX = 2048;  // max buckets for LDS-aggregated paths

__device__ __forceinline__ int rl(int v, int j) {
    return __builtin_amdgcn_readlane(v, j);
}
__device__ __forceinline__ float rlf(int v, int j) {
    return __uint_as_float((unsigned)__builtin_amdgcn_readlane(v, j));
}
__device__ __forceinline__ unsigned f2bf(float f) {  // f32 -> bf16 bits, RNE
    unsigned u = __float_as_uint(f);
    return (u + 0x7fffu + ((u >> 16) & 1u)) >> 16;
}

// ---------------------------------------------------------------------------
// prep: two block-ranges.
//  [0, PB)     : per-row L1 norm of x; pack xb = bf16x2(x * rnorm)
//  [PB, PB+64) : Wp pair-interleave  Wp[k2*256+2h+j] = W[h][2k2+j]
// ---------------------------------------------------------------------------
__global__ void prep_kernel(const float* __restrict__ x,
                            unsigned* __restrict__ xb,
                            const float* __restrict__ W,
                            float* __restrict__ Wp, int N, int PB) {
    int bid = blockIdx.x;
    if (bid < PB) {
        int row = bid * 4 + (threadIdx.x >> 6);
        int lane = threadIdx.x & 63;
        if (row >= N) return;
        float2 v = *((const float2*)(x + (size_t)row * HD) + lane);
        float s = fabsf(v.x) + fabsf(v.y);
#pragma unroll
        for (int m = 1; m < 64; m <<= 1) s += __shfl_xor(s, m, 64);
        float rn = 1.0f / fmaxf(s, 1e-12f);
        unsigned lo = f2bf(v.x * rn), hi = f2bf(v.y * rn);
        xb[(size_t)row * 64 + lane] = lo | (hi << 16);
    } else {
        int t = (bid - PB) * 256 + threadIdx.x;  // 0..16383
        int k2 = t >> 8, rem = t & 255, h = rem >> 1, j = rem & 1;
        Wp[t] = W[h * HD + 2 * k2 + j];
    }
}

// ---------------------------------------------------------------------------
// hist: LDS-aggregated bucket histogram. 256 thr x 16 edges = 4096/block.
// Global atomics: one per (block, nonzero bin) instead of one per edge.
// ---------------------------------------------------------------------------
__global__ void hist_kernel(const int* __restrict__ rows,
                            int* __restrict__ bcnt, int E, int NB) {
    __shared__ int lbin[NBMAX];
    if (NB <= NBMAX) {
        for (int i = threadIdx.x; i < NBMAX; i += 256) lbin[i] = 0;
        __syncthreads();
        int base = blockIdx.x * 4096;
#pragma unroll 4
        for (int i = 0; i < 16; ++i) {
            int e = base + i * 256 + threadIdx.x;
            if (e < E) atomicAdd(&lbin[rows[e] >> 6], 1);
        }
        __syncthreads();
        for (int i = threadIdx.x; i < NB; i += 256) {
            int c = lbin[i];
            if (c) atomicAdd(&bcnt[i], c);
        }
    } else {  // fallback: direct atomics
        int base = blockIdx.x * 4096;
        for (int i = 0; i < 16; ++i) {
            int e = base + i * 256 + threadIdx.x;
            if (e < E) atomicAdd(&bcnt[rows[e] >> 6], 1);
        }
    }
}

// ---------------------------------------------------------------------------
// bscan: single-block exclusive scan of NB bucket counts (NB <= 2048).
// ---------------------------------------------------------------------------
__global__ void bscan_kernel(const int* __restrict__ bcnt,
                             int* __restrict__ bbase,
                             int* __restrict__ bcursor, int NB) {
    __shared__ int lds[1024];
    int t = threadIdx.x;
    int i0 = 2 * t, i1 = 2 * t + 1;
    int c0 = (i0 < NB) ? bcnt[i0] : 0;
    int c1 = (i1 < NB) ? bcnt[i1] : 0;
    int s = c0 + c1;
    lds[t] = s;
    __syncthreads();
    for (int off = 1; off < 1024; off <<= 1) {
        int add = (t >= off) ? lds[t - off] : 0;
        __syncthreads();
        lds[t] += add;
        __syncthreads();
    }
    int excl = lds[t] - s;
    if (i0 < NB) { bbase[i0] = excl; bcursor[i0] = excl; }
    if (i1 < NB) { bbase[i1] = excl + c0; bcursor[i1] = excl + c0; }
}

// ---------------------------------------------------------------------------
// bscatter: aggregated scatter into bucket-grouped staging.
// 512 thr x 8 edges = 4096/block. Per block: LDS-rank each edge within its
// bucket, reserve a contiguous global range per nonzero bucket (ONE global
// atomic per bucket per block), then write bstage[base+rank].
// meta.x = col | (rowlocal<<17), meta.y = f32 bits of edge value.
// ---------------------------------------------------------------------------
__global__ void __launch_bounds__(512) bscatter_kernel(
    const int* __restrict__ rows, const int* __restrict__ cols,
    const float* __restrict__ vals, int* __restrict__ bcursor,
    int2* __restrict__ bstage, int E, int NB) {
    __shared__ int lbin[NBMAX];
    __shared__ int lbase[NBMAX];
    int tid = threadIdx.x;
    int base = blockIdx.x * 4096;
    if (NB <= NBMAX) {
        for (int i = tid; i < NBMAX; i += 512) lbin[i] = 0;
        __syncthreads();
        int bkt[8], cc[8], vv[8], rk[8];
#pragma unroll
        for (int i = 0; i < 8; ++i) {
            int e = base + i * 512 + tid;
            bkt[i] = -1;
            if (e < E) {
                int r = rows[e];
                cc[i] = cols[e] | ((r & 63) << 17);
                vv[i] = __float_as_int(vals[e]);
                bkt[i] = r >> 6;
                rk[i] = atomicAdd(&lbin[bkt[i]], 1);
            }
        }
        __syncthreads();
        for (int i = tid; i < NB; i += 512) {
            int c = lbin[i];
            if (c) lbase[i] = atomicAdd(&bcursor[i], c);
        }
        __syncthreads();
#pragma unroll
        for (int i = 0; i < 8; ++i) {
            if (bkt[i] >= 0)
                bstage[lbase[bkt[i]] + rk[i]] = make_int2(cc[i], vv[i]);
        }
    } else {  // fallback: per-edge cursor atomics
        for (int i = 0; i < 8; ++i) {
            int e = base + i * 512 + tid;
            if (e >= E) break;
            int r = rows[e], c = cols[e];
            int p = atomicAdd(&bcursor[r >> 6], 1);
            bstage[p] = make_int2(c | ((r & 63) << 17),
                                  __float_as_int(vals[e]));
        }
    }
}

// ---------------------------------------------------------------------------
// mega: per 64-row bucket (1024 threads = 16 waves x 4 rows):
//  - load bucket edges (<=2048) to registers
//  - in-LDS 64-bin counting sort -> local CSR in 12KB LDS (spill->bstage)
//  - stage Wp into 64KB LDS
//  - gather bf16 xb rows via readlane-broadcast metadata from LDS
//  - g = f @ W^T + b (readlane GEMM), L1-normalize, relu, residual, store
// ---------------------------------------------------------------------------
__global__ void __launch_bounds__(1024) mega_kernel(
    const float* __restrict__ x, const unsigned* __restrict__ xb,
    int2* bstage, const int* __restrict__ bbase, const int* __restrict__ bcnt,
    const float* __restrict__ Wp, const float* __restrict__ b,
    const float* __restrict__ tsp, float* __restrict__ out, int N) {
    __shared__ float wlds[HD * HD];  // 64 KiB
    __shared__ int2 sorted[CAP];     // 12 KiB
    __shared__ int lcnt[BROWS], lbeg[BROWS], lcur[BROWS];

    int tid = threadIdx.x;
    int bid = blockIdx.x;
    int bb = bbase[bid];
    int ct = bcnt[bid];

    if (tid < BROWS) lcnt[tid] = 0;

    // phase 1: bucket edges -> registers
    int2 m0 = make_int2(0, 0), m1 = make_int2(0, 0);
    bool e0 = tid < ct, e1 = tid + 1024 < ct;
    if (e0) m0 = bstage[bb + tid];
    if (e1) m1 = bstage[bb + tid + 1024];
    __syncthreads();  // lcnt zeroed + bstage reads drained

    // phase 2: LDS histogram of local rows
    if (e0) atomicAdd(&lcnt[(m0.x >> 17) & 63], 1);
    if (e1) atomicAdd(&lcnt[(m1.x >> 17) & 63], 1);
    __syncthreads();

    // phase 3: wave 0 exclusive-scans the 64 counts
    if (tid < 64) {
        int c = lcnt[tid];
        int s = c;
#pragma unroll
        for (int m = 1; m < 64; m <<= 1) {
            int t2 = __shfl_up(s, m, 64);
            if (tid >= m) s += t2;
        }
        lbeg[tid] = s - c;
        lcur[tid] = s - c;
    }
    __syncthreads();

    // phase 4: scatter edges into LDS-sorted local CSR (spill to bstage)
    if (e0) {
        int p = atomicAdd(&lcur[(m0.x >> 17) & 63], 1);
        if (p < CAP) sorted[p] = m0; else bstage[bb + p] = m0;
    }
    if (e1) {
        int p = atomicAdd(&lcur[(m1.x >> 17) & 63], 1);
        if (p < CAP) sorted[p] = m1; else bstage[bb + p] = m1;
    }
    // phase 5: stage Wp (independent LDS region)
    {
        const float4* s4 = (const float4*)Wp;
        float4* d4 = (float4*)wlds;
        for (int i = tid; i < HD * HD / 4; i += 1024) d4[i] = s4[i];
    }
    __syncthreads();  // last barrier

    int lane = tid & 63;
    int wid = tid >> 6;
    int r0 = bid * BROWS + wid * 4;
    if (r0 >= N) return;
    float ts = tsp[0];
    float b0 = b[2 * lane], b1 = b[2 * lane + 1];

    // ---- gather: accumulate 4 f-rows in registers ----
    float a0[4] = {0.f, 0.f, 0.f, 0.f}, a1[4] = {0.f, 0.f, 0.f, 0.f};
#pragma unroll
    for (int rr = 0; rr < 4; ++rr) {
        int row = r0 + rr;
        if (row >= N) break;
        int lr = wid * 4 + rr;
        int beg = lbeg[lr], cnt = lcnt[lr];
        float p0 = 0.f, q0 = 0.f, p1 = 0.f, q1 = 0.f;
        for (int jb = 0; jb < cnt; jb += 64) {
            int rem = cnt - jb;
            if (rem > 64) rem = 64;
            int2 meta = make_int2(0, 0);
            if (lane < rem) {
                int pidx = beg + jb + lane;
                meta = (pidx < CAP) ? sorted[pidx] : bstage[bb + pidx];
            }
            int j = 0;
            for (; j + 4 <= rem; j += 4) {
                int c0 = rl(meta.x, j) & 0x1FFFF;
                int c1 = rl(meta.x, j + 1) & 0x1FFFF;
                int c2 = rl(meta.x, j + 2) & 0x1FFFF;
                int c3 = rl(meta.x, j + 3) & 0x1FFFF;
                float s0 = rlf(meta.y, j), s1 = rlf(meta.y, j + 1);
                float s2 = rlf(meta.y, j + 2), s3 = rlf(meta.y, j + 3);
                unsigned u0 = xb[(size_t)c0 * 64 + lane];
                unsigned u1 = xb[(size_t)c1 * 64 + lane];
                unsigned u2 = xb[(size_t)c2 * 64 + lane];
                unsigned u3 = xb[(size_t)c3 * 64 + lane];
                p0 = fmaf(__uint_as_float(u0 << 16), s0, p0);
                q0 = fmaf(__uint_as_float(u0 & 0xffff0000u), s0, q0);
                p1 = fmaf(__uint_as_float(u1 << 16), s1, p1);
                q1 = fmaf(__uint_as_float(u1 & 0xffff0000u), s1, q1);
                p0 = fmaf(__uint_as_float(u2 << 16), s2, p0);
                q0 = fmaf(__uint_as_float(u2 & 0xffff0000u), s2, q0);
                p1 = fmaf(__uint_as_float(u3 << 16), s3, p1);
                q1 = fmaf(__uint_as_float(u3 & 0xffff0000u), s3, q1);
            }
            for (; j < rem; ++j) {
                int c0 = rl(meta.x, j) & 0x1FFFF;
                float s0 = rlf(meta.y, j);
                unsigned u0 = xb[(size_t)c0 * 64 + lane];
                p0 = fmaf(__uint_as_float(u0 << 16), s0, p0);
                q0 = fmaf(__uint_as_float(u0 & 0xffff0000u), s0, q0);
            }
        }
        a0[rr] = p0 + p1;
        a1[rr] = q0 + q1;
    }

    // ---- GEMM: g[c] = dot(f, W[c,:]) for c = 2*lane, 2*lane+1 ----
    float g0[4] = {0.f, 0.f, 0.f, 0.f}, g1[4] = {0.f, 0.f, 0.f, 0.f};
#pragma unroll 8
    for (int k2 = 0; k2 < 64; ++k2) {
        float4 w = *((const float4*)(wlds + k2 * 256) + lane);
#pragma unroll
        for (int rr = 0; rr < 4; ++rr) {
            float fk0 = __uint_as_float(
                __builtin_amdgcn_readlane(__float_as_uint(a0[rr]), k2));
            float fk1 = __uint_as_float(
                __builtin_amdgcn_readlane(__float_as_uint(a1[rr]), k2));
            g0[rr] = fmaf(fk0, w.x, g0[rr]);
            g0[rr] = fmaf(fk1, w.y, g0[rr]);
            g1[rr] = fmaf(fk0, w.z, g1[rr]);
            g1[rr] = fmaf(fk1, w.w, g1[rr]);
        }
    }

    // ---- epilogue: bias, L1 normalize, relu, residual ----
#pragma unroll
    for (int rr = 0; rr < 4; ++rr) {
        int row = r0 + rr;
        if (row >= N) break;
        float G0 = g0[rr] + b0, G1 = g1[rr] + b1;
        float s = fabsf(G0) + fabsf(G1);
#pragma unroll
        for (int m = 1; m < 64; m <<= 1) s += __shfl_xor(s, m, 64);
        float rn = 1.0f / fmaxf(s, 1e-12f);
        G0 = fmaxf(G0 * rn, 0.f);
        G1 = fmaxf(G1 * rn, 0.f);
        float2 xv = *((const float2*)(x + (size_t)row * HD) + lane);
        float2 o;
        o.x = fmaf(ts, G0, xv.x);
        o.y = fmaf(ts, G1, xv.y);
        *((float2*)(out + (size_t)row * HD) + lane) = o;
    }
}

extern "C" void kernel_launch(void* const* d_in, const int* in_sizes, int n_in,
                              void* d_out, int out_size, void* d_ws,
                              size_t ws_size, hipStream_t stream) {
    const float* x = (const float*)d_in[0];
    const int* Ar = (const int*)d_in[1];
    const int* Ac = (const int*)d_in[2];
    const float* Av = (const float*)d_in[3];
    const float* W = (const float*)d_in[4];
    const float* b = (const float*)d_in[5];
    const float* ts = (const float*)d_in[6];

    int N = in_sizes[0] / HD;
    int E = in_sizes[1];
    float* out = (float*)d_out;

    int NB = (N + BROWS - 1) / BROWS;  // buckets == mega blocks

    char* ws = (char*)d_ws;
    size_t o = 0;
    auto take = [&](size_t bytes) {
        void* p = ws + o;
        o += (bytes + 511) & ~(size_t)511;
        return p;
    };
    int* bcnt = (int*)take((size_t)NB * 4);
    int* bbase = (int*)take((size_t)NB * 4);
    int* bcursor = (int*)take((size_t)NB * 4);
    float* Wp = (float*)take((size_t)HD * HD * 4);
    unsigned* xb = (unsigned*)take((size_t)N * 64 * 4);
    int2* bstage = (int2*)take((size_t)E * 8);

    hipMemsetAsync(bcnt, 0, (size_t)NB * 4, stream);

    int PB = (N + 3) / 4;
    prep_kernel<<<PB + 64, 256, 0, stream>>>(x, xb, W, Wp, N, PB);
    hist_kernel<<<(E + 4095) / 4096, 256, 0, stream>>>(Ar, bcnt, E, NB);
    bscan_kernel<<<1, 1024, 0, stream>>>(bcnt, bbase, bcursor, NB);
    bscatter_kernel<<<(E + 4095) / 4096, 512, 0, stream>>>(Ar, Ac, Av, bcursor,
                                                           bstage, E, NB);
    mega_kernel<<<NB, 1024, 0, stream>>>(x, xb, bstage, bbase, bcnt, Wp, b, ts,
                                         out, N);
}

// Round 6
// 160.911 us; speedup vs baseline: 4.1160x; 1.4242x over previous
//
#include <hip/hip_runtime.h>

constexpr int HD = 128;      // hidden size
constexpr int BROWS = 64;    // rows per bucket == rows per mega-block
constexpr int CAP = 2048;    // LDS sorted-edge capacity per bucket
constexpr int NBMAX = 2048;  // max buckets for LDS-aggregated paths

typedef __attribute__((ext_vector_type(8))) short short8v;  // 8 bf16 (4 VGPR)
typedef __attribute__((ext_vector_type(4))) float f32x4;

__device__ __forceinline__ int rl(int v, int j) {
    return __builtin_amdgcn_readlane(v, j);
}
__device__ __forceinline__ float rlf(int v, int j) {
    return __uint_as_float((unsigned)__builtin_amdgcn_readlane(v, j));
}
__device__ __forceinline__ unsigned f2bf(float f) {  // f32 -> bf16 bits, RNE
    unsigned u = __float_as_uint(f);
    return (u + 0x7fffu + ((u >> 16) & 1u)) >> 16;
}

// ---------------------------------------------------------------------------
// prep: two block-ranges.
//  [0, PB)     : per-row L1 norm of x; pack xb = bf16x2(x * rnorm)
//  [PB, PB+32) : Wb bf16 pack in B-fragment layout with XOR swizzle:
//                Wb_byte[(col*256 + k*2) ^ ((col&7)<<4)] = bf16(W[col][k])
// ---------------------------------------------------------------------------
__global__ void prep_kernel(const float* __restrict__ x,
                            unsigned* __restrict__ xb,
                            const float* __restrict__ W,
                            unsigned* __restrict__ Wb, int N, int PB) {
    int bid = blockIdx.x;
    if (bid < PB) {
        int row = bid * 4 + (threadIdx.x >> 6);
        int lane = threadIdx.x & 63;
        if (row >= N) return;
        float2 v = *((const float2*)(x + (size_t)row * HD) + lane);
        float s = fabsf(v.x) + fabsf(v.y);
#pragma unroll
        for (int m = 1; m < 64; m <<= 1) s += __shfl_xor(s, m, 64);
        float rn = 1.0f / fmaxf(s, 1e-12f);
        unsigned lo = f2bf(v.x * rn), hi = f2bf(v.y * rn);
        xb[(size_t)row * 64 + lane] = lo | (hi << 16);
    } else {
        int t = (bid - PB) * 256 + threadIdx.x;  // 0..8191 => (col, k2)
        int col = t >> 6, k2 = t & 63;
        float w0 = W[col * HD + 2 * k2];
        float w1 = W[col * HD + 2 * k2 + 1];
        unsigned pk = f2bf(w0) | (f2bf(w1) << 16);
        int byte = (col * 256 + k2 * 4) ^ ((col & 7) << 4);
        *(unsigned*)((char*)Wb + byte) = pk;
    }
}

// ---------------------------------------------------------------------------
// hist: LDS-aggregated bucket histogram. 256 thr x 16 edges = 4096/block.
// ---------------------------------------------------------------------------
__global__ void hist_kernel(const int* __restrict__ rows,
                            int* __restrict__ bcnt, int E, int NB) {
    __shared__ int lbin[NBMAX];
    if (NB <= NBMAX) {
        for (int i = threadIdx.x; i < NBMAX; i += 256) lbin[i] = 0;
        __syncthreads();
        int base = blockIdx.x * 4096;
#pragma unroll 4
        for (int i = 0; i < 16; ++i) {
            int e = base + i * 256 + threadIdx.x;
            if (e < E) atomicAdd(&lbin[rows[e] >> 6], 1);
        }
        __syncthreads();
        for (int i = threadIdx.x; i < NB; i += 256) {
            int c = lbin[i];
            if (c) atomicAdd(&bcnt[i], c);
        }
    } else {
        int base = blockIdx.x * 4096;
        for (int i = 0; i < 16; ++i) {
            int e = base + i * 256 + threadIdx.x;
            if (e < E) atomicAdd(&bcnt[rows[e] >> 6], 1);
        }
    }
}

// ---------------------------------------------------------------------------
// bscan: single-block exclusive scan of NB bucket counts (NB <= 2048).
// ---------------------------------------------------------------------------
__global__ void bscan_kernel(const int* __restrict__ bcnt,
                             int* __restrict__ bbase,
                             int* __restrict__ bcursor, int NB) {
    __shared__ int lds[1024];
    int t = threadIdx.x;
    int i0 = 2 * t, i1 = 2 * t + 1;
    int c0 = (i0 < NB) ? bcnt[i0] : 0;
    int c1 = (i1 < NB) ? bcnt[i1] : 0;
    int s = c0 + c1;
    lds[t] = s;
    __syncthreads();
    for (int off = 1; off < 1024; off <<= 1) {
        int add = (t >= off) ? lds[t - off] : 0;
        __syncthreads();
        lds[t] += add;
        __syncthreads();
    }
    int excl = lds[t] - s;
    if (i0 < NB) { bbase[i0] = excl; bcursor[i0] = excl; }
    if (i1 < NB) { bbase[i1] = excl + c0; bcursor[i1] = excl + c0; }
}

// ---------------------------------------------------------------------------
// bscatter: aggregated scatter into bucket-grouped staging.
// ---------------------------------------------------------------------------
__global__ void __launch_bounds__(512) bscatter_kernel(
    const int* __restrict__ rows, const int* __restrict__ cols,
    const float* __restrict__ vals, int* __restrict__ bcursor,
    int2* __restrict__ bstage, int E, int NB) {
    __shared__ int lbin[NBMAX];
    __shared__ int lbase[NBMAX];
    int tid = threadIdx.x;
    int base = blockIdx.x * 4096;
    if (NB <= NBMAX) {
        for (int i = tid; i < NBMAX; i += 512) lbin[i] = 0;
        __syncthreads();
        int bkt[8], cc[8], vv[8], rk[8];
#pragma unroll
        for (int i = 0; i < 8; ++i) {
            int e = base + i * 512 + tid;
            bkt[i] = -1;
            if (e < E) {
                int r = rows[e];
                cc[i] = cols[e] | ((r & 63) << 17);
                vv[i] = __float_as_int(vals[e]);
                bkt[i] = r >> 6;
                rk[i] = atomicAdd(&lbin[bkt[i]], 1);
            }
        }
        __syncthreads();
        for (int i = tid; i < NB; i += 512) {
            int c = lbin[i];
            if (c) lbase[i] = atomicAdd(&bcursor[i], c);
        }
        __syncthreads();
#pragma unroll
        for (int i = 0; i < 8; ++i) {
            if (bkt[i] >= 0)
                bstage[lbase[bkt[i]] + rk[i]] = make_int2(cc[i], vv[i]);
        }
    } else {
        for (int i = 0; i < 8; ++i) {
            int e = base + i * 512 + tid;
            if (e >= E) break;
            int r = rows[e], c = cols[e];
            int p = atomicAdd(&bcursor[r >> 6], 1);
            bstage[p] = make_int2(c | ((r & 63) << 17),
                                  __float_as_int(vals[e]));
        }
    }
}

// ---------------------------------------------------------------------------
// mega: per 64-row bucket (1024 threads = 16 waves):
//  1. bucket edges -> regs; in-LDS 64-bin counting sort -> local CSR
//  2. gather: each wave accumulates 4 f-rows in f32 regs (bf16 xb loads)
//  3. f -> bf16 -> swizzled LDS A-tile
//  4. GEMM via mfma_f32_16x16x32_bf16 (wave = 16x32 output tile)
//  5. bias, row-L1 via shfl + LDS float atomics, relu, residual, store
// ---------------------------------------------------------------------------
__global__ void __launch_bounds__(1024) mega_kernel(
    const float* __restrict__ x, const unsigned* __restrict__ xb,
    int2* bstage, const int* __restrict__ bbase, const int* __restrict__ bcnt,
    const unsigned* __restrict__ Wb, const float* __restrict__ bias,
    const float* __restrict__ tsp, float* __restrict__ out, int N) {
    __shared__ char wb_raw[HD * HD * 2];     // 32 KiB bf16 W, B-layout, swz
    __shared__ char fb_raw[BROWS * HD * 2];  // 16 KiB bf16 F, A-layout, swz
    __shared__ int2 sorted[CAP];             // 16 KiB
    __shared__ int lcnt[BROWS], lbeg[BROWS], lcur[BROWS];
    __shared__ float rowsum[BROWS];

    int tid = threadIdx.x;
    int bid = blockIdx.x;
    int bb = bbase[bid];
    int ct = bcnt[bid];

    if (tid < BROWS) lcnt[tid] = 0;

    // phase 1: bucket edges -> registers
    int2 m0 = make_int2(0, 0), m1 = make_int2(0, 0);
    bool e0 = tid < ct, e1 = tid + 1024 < ct;
    if (e0) m0 = bstage[bb + tid];
    if (e1) m1 = bstage[bb + tid + 1024];
    __syncthreads();

    // phase 2: LDS histogram of local rows
    if (e0) atomicAdd(&lcnt[(m0.x >> 17) & 63], 1);
    if (e1) atomicAdd(&lcnt[(m1.x >> 17) & 63], 1);
    __syncthreads();

    // phase 3: wave 0 exclusive-scans the 64 counts
    if (tid < 64) {
        int c = lcnt[tid];
        int s = c;
#pragma unroll
        for (int m = 1; m < 64; m <<= 1) {
            int t2 = __shfl_up(s, m, 64);
            if (tid >= m) s += t2;
        }
        lbeg[tid] = s - c;
        lcur[tid] = s - c;
    }
    __syncthreads();

    // phase 4: scatter edges into LDS-sorted local CSR (+ stage Wb)
    if (e0) {
        int p = atomicAdd(&lcur[(m0.x >> 17) & 63], 1);
        if (p < CAP) sorted[p] = m0; else bstage[bb + p] = m0;
    }
    if (e1) {
        int p = atomicAdd(&lcur[(m1.x >> 17) & 63], 1);
        if (p < CAP) sorted[p] = m1; else bstage[bb + p] = m1;
    }
    {
        const float4* s4 = (const float4*)Wb;
        float4* d4 = (float4*)wb_raw;
        for (int i = tid; i < HD * HD * 2 / 16; i += 1024) d4[i] = s4[i];
    }
    __syncthreads();

    int lane = tid & 63;
    int wid = tid >> 6;
    float ts = tsp[0];

    // ---- gather: accumulate 4 f-rows (f32) per wave ----
    float a0[4] = {0.f, 0.f, 0.f, 0.f}, a1[4] = {0.f, 0.f, 0.f, 0.f};
#pragma unroll
    for (int rr = 0; rr < 4; ++rr) {
        int lr = wid * 4 + rr;
        int beg = lbeg[lr], cnt = lcnt[lr];
        float p0 = 0.f, q0 = 0.f, p1 = 0.f, q1 = 0.f;
        for (int jb = 0; jb < cnt; jb += 64) {
            int rem = cnt - jb;
            if (rem > 64) rem = 64;
            int2 meta = make_int2(0, 0);
            if (lane < rem) {
                int pidx = beg + jb + lane;
                meta = (pidx < CAP) ? sorted[pidx] : bstage[bb + pidx];
            }
            int j = 0;
            for (; j + 4 <= rem; j += 4) {
                int c0 = rl(meta.x, j) & 0x1FFFF;
                int c1 = rl(meta.x, j + 1) & 0x1FFFF;
                int c2 = rl(meta.x, j + 2) & 0x1FFFF;
                int c3 = rl(meta.x, j + 3) & 0x1FFFF;
                float s0 = rlf(meta.y, j), s1 = rlf(meta.y, j + 1);
                float s2 = rlf(meta.y, j + 2), s3 = rlf(meta.y, j + 3);
                unsigned u0 = xb[(size_t)c0 * 64 + lane];
                unsigned u1 = xb[(size_t)c1 * 64 + lane];
                unsigned u2 = xb[(size_t)c2 * 64 + lane];
                unsigned u3 = xb[(size_t)c3 * 64 + lane];
                p0 = fmaf(__uint_as_float(u0 << 16), s0, p0);
                q0 = fmaf(__uint_as_float(u0 & 0xffff0000u), s0, q0);
                p1 = fmaf(__uint_as_float(u1 << 16), s1, p1);
                q1 = fmaf(__uint_as_float(u1 & 0xffff0000u), s1, q1);
                p0 = fmaf(__uint_as_float(u2 << 16), s2, p0);
                q0 = fmaf(__uint_as_float(u2 & 0xffff0000u), s2, q0);
                p1 = fmaf(__uint_as_float(u3 << 16), s3, p1);
                q1 = fmaf(__uint_as_float(u3 & 0xffff0000u), s3, q1);
            }
            for (; j < rem; ++j) {
                int c0 = rl(meta.x, j) & 0x1FFFF;
                float s0 = rlf(meta.y, j);
                unsigned u0 = xb[(size_t)c0 * 64 + lane];
                p0 = fmaf(__uint_as_float(u0 << 16), s0, p0);
                q0 = fmaf(__uint_as_float(u0 & 0xffff0000u), s0, q0);
            }
        }
        a0[rr] = p0 + p1;
        a1[rr] = q0 + q1;
    }

    // ---- phase C: f -> bf16 swizzled LDS A-tile; init rowsum ----
#pragma unroll
    for (int rr = 0; rr < 4; ++rr) {
        int row = wid * 4 + rr;  // local row
        unsigned pk = f2bf(a0[rr]) | (f2bf(a1[rr]) << 16);
        int byte = (row * 256 + lane * 4) ^ ((row & 7) << 4);
        *(unsigned*)(fb_raw + byte) = pk;
    }
    if (tid < BROWS) rowsum[tid] = 0.f;
    __syncthreads();

    // ---- MFMA GEMM: wave -> 16-row x 32-col output tile ----
    int rt = wid >> 2;         // row-tile 0..3
    int ct0 = (wid & 3) * 2;   // first col-tile (of 8)
    int c = lane & 15;
    int kg = lane >> 4;
    int arow = rt * 16 + c;
    int bcol0 = ct0 * 16 + c;
    int bcol1 = bcol0 + 16;
    f32x4 acc0 = {0.f, 0.f, 0.f, 0.f}, acc1 = {0.f, 0.f, 0.f, 0.f};
#pragma unroll
    for (int kk = 0; kk < 4; ++kk) {
        int ka = kg * 16 + kk * 64;  // byte offset of this lane's k-chunk
        short8v af = *(const short8v*)(fb_raw +
                                       ((arow * 256 + ka) ^ ((arow & 7) << 4)));
        short8v bf0 = *(const short8v*)(wb_raw +
                                        ((bcol0 * 256 + ka) ^ ((bcol0 & 7) << 4)));
        short8v bf1 = *(const short8v*)(wb_raw +
                                        ((bcol1 * 256 + ka) ^ ((bcol1 & 7) << 4)));
        acc0 = __builtin_amdgcn_mfma_f32_16x16x32_bf16(af, bf0, acc0, 0, 0, 0);
        acc1 = __builtin_amdgcn_mfma_f32_16x16x32_bf16(af, bf1, acc1, 0, 0, 0);
    }

    // ---- epilogue: bias, row-L1 reduce, normalize, relu, residual ----
    float bias0 = bias[bcol0];
    float bias1 = bias[bcol1];
    float g0r[4], g1r[4];
#pragma unroll
    for (int r = 0; r < 4; ++r) {
        float v0 = acc0[r] + bias0;
        float v1 = acc1[r] + bias1;
        g0r[r] = v0;
        g1r[r] = v1;
        float s = fabsf(v0) + fabsf(v1);
        s += __shfl_xor(s, 1, 64);
        s += __shfl_xor(s, 2, 64);
        s += __shfl_xor(s, 4, 64);
        s += __shfl_xor(s, 8, 64);
        if (c == 0) atomicAdd(&rowsum[rt * 16 + kg * 4 + r], s);
    }
    __syncthreads();
#pragma unroll
    for (int r = 0; r < 4; ++r) {
        int lrow = rt * 16 + kg * 4 + r;
        int row = bid * BROWS + lrow;
        if (row < N) {
            float rn = 1.0f / fmaxf(rowsum[lrow], 1e-12f);
            float G0 = fmaxf(g0r[r] * rn, 0.f);
            float G1 = fmaxf(g1r[r] * rn, 0.f);
            float x0 = x[(size_t)row * HD + bcol0];
            float x1 = x[(size_t)row * HD + bcol1];
            out[(size_t)row * HD + bcol0] = fmaf(ts, G0, x0);
            out[(size_t)row * HD + bcol1] = fmaf(ts, G1, x1);
        }
    }
}

extern "C" void kernel_launch(void* const* d_in, const int* in_sizes, int n_in,
                              void* d_out, int out_size, void* d_ws,
                              size_t ws_size, hipStream_t stream) {
    const float* x = (const float*)d_in[0];
    const int* Ar = (const int*)d_in[1];
    const int* Ac = (const int*)d_in[2];
    const float* Av = (const float*)d_in[3];
    const float* W = (const float*)d_in[4];
    const float* b = (const float*)d_in[5];
    const float* ts = (const float*)d_in[6];

    int N = in_sizes[0] / HD;
    int E = in_sizes[1];
    float* out = (float*)d_out;

    int NB = (N + BROWS - 1) / BROWS;

    char* ws = (char*)d_ws;
    size_t o = 0;
    auto take = [&](size_t bytes) {
        void* p = ws + o;
        o += (bytes + 511) & ~(size_t)511;
        return p;
    };
    int* bcnt = (int*)take((size_t)NB * 4);
    int* bbase = (int*)take((size_t)NB * 4);
    int* bcursor = (int*)take((size_t)NB * 4);
    unsigned* Wb = (unsigned*)take((size_t)HD * HD * 2);
    unsigned* xb = (unsigned*)take((size_t)N * 64 * 4);
    int2* bstage = (int2*)take((size_t)E * 8);

    hipMemsetAsync(bcnt, 0, (size_t)NB * 4, stream);

    int PB = (N + 3) / 4;
    prep_kernel<<<PB + 32, 256, 0, stream>>>(x, xb, W, Wb, N, PB);
    hist_kernel<<<(E + 4095) / 4096, 256, 0, stream>>>(Ar, bcnt, E, NB);
    bscan_kernel<<<1, 1024, 0, stream>>>(bcnt, bbase, bcursor, NB);
    bscatter_kernel<<<(E + 4095) / 4096, 512, 0, stream>>>(Ar, Ac, Av, bcursor,
                                                           bstage, E, NB);
    mega_kernel<<<NB, 1024, 0, stream>>>(x, xb, bstage, bbase, bcnt, Wb, b, ts,
                                         out, N);
}